// Round 2
// baseline (470.427 us; speedup 1.0000x reference)
//
#include <hip/hip_runtime.h>

typedef unsigned int uint;
typedef unsigned short ushort_t;
typedef short bf16x8 __attribute__((ext_vector_type(8)));
typedef float f32x4 __attribute__((ext_vector_type(4)));

// ---------- bf16 helpers ----------
__device__ __forceinline__ ushort_t f2bf(float f) {
  uint u = __builtin_bit_cast(uint, f);
  u += 0x7fffu + ((u >> 16) & 1u);
  return (ushort_t)(u >> 16);
}
__device__ __forceinline__ float bf2f(ushort_t s) {
  return __builtin_bit_cast(float, (uint)s << 16);
}
__device__ __forceinline__ bf16x8 ld_frag(const ushort_t* p) {
  return __builtin_bit_cast(bf16x8, *(const uint4*)p);
}
// force a wave-uniform load into an SGPR (keeps the 6x6 fuse weights off VGPRs)
__device__ __forceinline__ float uload(const float* p) {
  return __builtin_bit_cast(float,
      __builtin_amdgcn_readfirstlane(__builtin_bit_cast(int, *p)));
}

// ---------- Kernel 1: depthwise conv 3x3 s2 p1 + LayerNorm -> bf16 ----------
__global__ __launch_bounds__(384) void k_convln(
    const float* __restrict__ x, const float* __restrict__ wc,
    const float* __restrict__ g, const float* __restrict__ bb,
    ushort_t* __restrict__ qout)
{
  const int b  = blockIdx.x / 784;
  const int t  = blockIdx.x % 784;
  const int oy = t / 28, ox = t % 28;
  const int c  = threadIdx.x;
  const float* xb = x + (size_t)b * 3136 * 384 + c;
  float acc = 0.f;
  #pragma unroll
  for (int ky = 0; ky < 3; ky++) {
    const int iy = 2 * oy - 1 + ky;
    if (iy < 0 || iy >= 56) continue;
    #pragma unroll
    for (int kx = 0; kx < 3; kx++) {
      const int ix = 2 * ox - 1 + kx;
      if (ix < 0 || ix >= 56) continue;
      acc += wc[c * 9 + ky * 3 + kx] * xb[(size_t)(iy * 56 + ix) * 384];
    }
  }
  float s = acc, s2 = acc * acc;
  #pragma unroll
  for (int off = 32; off >= 1; off >>= 1) {
    s  += __shfl_xor(s,  off);
    s2 += __shfl_xor(s2, off);
  }
  __shared__ float ps[6], ps2[6];
  if ((c & 63) == 0) { ps[c >> 6] = s; ps2[c >> 6] = s2; }
  __syncthreads();
  float S = 0.f, S2 = 0.f;
  #pragma unroll
  for (int i = 0; i < 6; i++) { S += ps[i]; S2 += ps2[i]; }
  const float mu  = S * (1.f / 384.f);
  const float var = S2 * (1.f / 384.f) - mu * mu;
  const float inv = rsqrtf(var + 1e-5f);
  qout[((size_t)b * 784 + t) * 384 + c] = f2bf((acc - mu) * inv * g[c] + bb[c]);
}

// ---------- Kernel 2: 2x2 average pool -> bf16 ----------
__global__ __launch_bounds__(256) void k_pool(
    const float* __restrict__ x, ushort_t* __restrict__ kvout)
{
  const int idx = blockIdx.x * 256 + threadIdx.x;
  const int c = idx % 384;
  const int t = (idx / 384) % 784;
  const int b = idx / (384 * 784);
  const int ty = t / 28, tx = t % 28;
  const float* xb = x + (size_t)b * 3136 * 384 + c;
  const int r0 = (2 * ty) * 56 + 2 * tx;
  const float v = xb[(size_t)r0 * 384] + xb[(size_t)(r0 + 1) * 384]
                + xb[(size_t)(r0 + 56) * 384] + xb[(size_t)(r0 + 57) * 384];
  kvout[idx] = f2bf(v * 0.25f);
}

// ---------- Kernel 3: weights f32 -> bf16 ----------
__global__ __launch_bounds__(256) void k_wcvt(
    const float* __restrict__ a, const float* __restrict__ b,
    const float* __restrict__ c, const float* __restrict__ d,
    ushort_t* __restrict__ oa, ushort_t* __restrict__ ob,
    ushort_t* __restrict__ oc, ushort_t* __restrict__ od)
{
  const int i = blockIdx.x * 256 + threadIdx.x;
  if (i < 147456) {
    oa[i] = f2bf(a[i]); ob[i] = f2bf(b[i]);
    oc[i] = f2bf(c[i]); od[i] = f2bf(d[i]);
  }
}

// ---------- Kernel 4: dense MFMA GEMM, M=6272 N=384 K=384 ----------
// Y[m,n] = sum_k X[m,k]*W[n,k]. 128x128 tile, 4 waves (2x2), 4x4 16x16 tiles.
// MODE 0: bf16 row-major out; MODE 1: bf16 transposed (b,384,784) out (for V);
// MODE 2: f32 +bias out.
template<int MODE>
__global__ __launch_bounds__(256) void k_gemm(
    const ushort_t* __restrict__ X, const ushort_t* __restrict__ W,
    const float* __restrict__ bias, void* __restrict__ Y)
{
  __shared__ ushort_t As[128][40];  // pad 32->40: row stride 20 words (2-way, free)
  __shared__ ushort_t Bs[128][40];
  const int tid = threadIdx.x, w = tid >> 6, lane = tid & 63;
  const int quad = lane >> 4, r = lane & 15;
  const int m0 = blockIdx.y * 128, n0 = blockIdx.x * 128;
  const int wm = w >> 1, wn = w & 1;
  const int lr = tid >> 2, lc = (tid & 3) << 3;
  const ushort_t* xp = X + (size_t)(m0 + lr) * 384 + lc;
  const ushort_t* wp = W + (size_t)(n0 + lr) * 384 + lc;
  f32x4 acc[4][4] = {};
  for (int k0 = 0; k0 < 384; k0 += 32) {
    __syncthreads();
    *(uint4*)&As[lr][lc]      = *(const uint4*)(xp + k0);
    *(uint4*)&As[lr + 64][lc] = *(const uint4*)(xp + (size_t)64 * 384 + k0);
    *(uint4*)&Bs[lr][lc]      = *(const uint4*)(wp + k0);
    *(uint4*)&Bs[lr + 64][lc] = *(const uint4*)(wp + (size_t)64 * 384 + k0);
    __syncthreads();
    bf16x8 af[4], bf_[4];
    #pragma unroll
    for (int mt = 0; mt < 4; mt++) af[mt]  = *(const bf16x8*)&As[wm * 64 + mt * 16 + r][quad * 8];
    #pragma unroll
    for (int nt = 0; nt < 4; nt++) bf_[nt] = *(const bf16x8*)&Bs[wn * 64 + nt * 16 + r][quad * 8];
    #pragma unroll
    for (int mt = 0; mt < 4; mt++)
      #pragma unroll
      for (int nt = 0; nt < 4; nt++)
        acc[mt][nt] = __builtin_amdgcn_mfma_f32_16x16x32_bf16(af[mt], bf_[nt], acc[mt][nt], 0, 0, 0);
  }
  #pragma unroll
  for (int mt = 0; mt < 4; mt++) {
    #pragma unroll
    for (int nt = 0; nt < 4; nt++) {
      #pragma unroll
      for (int i = 0; i < 4; i++) {
        const int row = m0 + wm * 64 + mt * 16 + quad * 4 + i;
        const int col = n0 + wn * 64 + nt * 16 + r;
        const float v = acc[mt][nt][i];
        if constexpr (MODE == 2) {
          ((float*)Y)[(size_t)row * 384 + col] = v + bias[col];
        } else if constexpr (MODE == 0) {
          ((ushort_t*)Y)[(size_t)row * 384 + col] = f2bf(v);
        } else {
          const int bb = row / 784, tt = row % 784;
          ((ushort_t*)Y)[((size_t)bb * 384 + col) * 784 + tt] = f2bf(v);
        }
      }
    }
  }
}

// ---------- Kernel 5: premix res_attn with w_fuse[:,6:12] at source res ----
// Z[b][o][s][t] = sum_c wf2[o][c] * ra[b][c][s][t]   (f32, 196x784 planes)
__global__ __launch_bounds__(256) void k_premix(
    const float* __restrict__ ra, const float* __restrict__ w_fuse,
    float* __restrict__ Z)
{
  const int NP = 196 * 784 / 4;             // float4 chunks per plane = 38416
  const int idx = blockIdx.x * 256 + threadIdx.x;
  if (idx >= 8 * NP) return;
  const int b = idx / NP, st = idx % NP;
  const f32x4* rb = (const f32x4*)(ra + (size_t)b * 6 * 153664) + st;
  f32x4 v[6];
  #pragma unroll
  for (int c = 0; c < 6; c++) v[c] = rb[(size_t)c * NP];
  f32x4* zb = (f32x4*)(Z + (size_t)b * 6 * 153664) + st;
  #pragma unroll
  for (int o = 0; o < 6; o++) {
    f32x4 acc = {};
    #pragma unroll
    for (int c = 0; c < 6; c++) acc += uload(w_fuse + o * 12 + 6 + c) * v[c];
    zb[(size_t)o * NP] = acc;
  }
}

// ---------- Kernel 6: fused flash attention (QK^T + head-mix + res + softmax
//            + PV), scores never leave registers/LDS -------------------------
// Grid (49, 8): block owns 16 query rows (l0..l0+15) of one batch.
// 4 waves split the T=784 key range round-robin over 32-wide tiles; online
// softmax with per-wave deferred max (THR=8); cross-wave merge through LDS.
__global__ __launch_bounds__(256, 2) void k_flash(
    const ushort_t* __restrict__ Qb, const ushort_t* __restrict__ Kb,
    const ushort_t* __restrict__ Vt, const float* __restrict__ Z,
    const float* __restrict__ w_fuse, const float* __restrict__ b_fuse,
    ushort_t* __restrict__ O)
{
  const int tid = threadIdx.x, w = tid >> 6, lane = tid & 63;
  const int quad = lane >> 4, r = lane & 15;
  const int b  = blockIdx.y;
  const int l0 = blockIdx.x * 16;

  __shared__ ushort_t Qs[16][424];          // stride 424 elems = 212 dw (20 mod 32)
  __shared__ ushort_t Pl[4][16][40];        // per-wave P tile, m97-style pad
  __shared__ float accbuf[4][16][64];
  __shared__ float sbuf[4][16];
  __shared__ float wmbuf[4][6];

  // stage Q tile: 16 rows x 384 bf16 = 768 8-elem chunks, 3 per thread
  #pragma unroll
  for (int c = 0; c < 3; c++) {
    const int idx = c * 256 + tid;
    const int row = idx / 48, col8 = idx % 48;
    *(uint4*)&Qs[row][col8 * 8] =
        *(const uint4*)(Qb + ((size_t)(b * 784 + l0 + row)) * 384 + col8 * 8);
  }
  __syncthreads();

  // fuse weights (scale folded) into SGPRs
  float wfs[6][6], bfu[6];
  #pragma unroll
  for (int o = 0; o < 6; o++) {
    bfu[o] = uload(b_fuse + o);
    #pragma unroll
    for (int h = 0; h < 6; h++)
      wfs[o][h] = uload(w_fuse + o * 12 + h) * 0.05103103630798288f; // 384^-0.5
  }

  // bilinear constants for this lane's 4 output rows (l = l0 + quad*4 + i)
  int p00a[4], p01a[4], p10a[4];
  float fxa[4], fya[4];
  #pragma unroll
  for (int i = 0; i < 4; i++) {
    const int l = l0 + quad * 4 + i;
    const int Y = l / 28, X = l % 28;
    const float cy = fminf(fmaxf((float)Y * 0.5f - 0.25f, 0.f), 13.f);
    const float cx = fminf(fmaxf((float)X * 0.5f - 0.25f, 0.f), 13.f);
    const int y0 = (int)cy, y1 = min(y0 + 1, 13);
    const int x0 = (int)cx, x1 = min(x0 + 1, 13);
    fya[i] = cy - (float)y0;
    fxa[i] = cx - (float)x0;
    p00a[i] = (y0 * 14 + x0) * 784;
    p01a[i] = (y0 * 14 + x1) * 784;
    p10a[i] = (y1 * 14 + x0) * 784;
  }

  f32x4 accp[6][4] = {};                    // PV accumulators [o][nt]
  float srow[6][4] = {};                    // per-row exp sums [o][i]
  float mo[6];
  #pragma unroll
  for (int o = 0; o < 6; o++) mo[o] = -1e30f;

  for (int tt = w; tt < 25; tt += 4) {      // wave-private t-tiles (32 wide)
    const int t0 = tt * 32;
    const int nj = (t0 + 32 <= 784) ? 2 : 1; // tile 24 is 16 wide

    // ---- QK^T for all 6 heads (A from LDS, B direct from L2-hot Kb) ----
    f32x4 accs[6][2] = {};
    #pragma unroll
    for (int j = 0; j < 2; j++) {
      if (j < nj) {
        const ushort_t* kp = Kb + ((size_t)(b * 784 + t0 + j * 16 + r)) * 384;
        #pragma unroll
        for (int h = 0; h < 6; h++) {
          const bf16x8 a0 = *(const bf16x8*)&Qs[r][h * 64 + quad * 8];
          const bf16x8 a1 = *(const bf16x8*)&Qs[r][h * 64 + 32 + quad * 8];
          accs[h][j] = __builtin_amdgcn_mfma_f32_16x16x32_bf16(
              a0, ld_frag(kp + h * 64 + quad * 8),      accs[h][j], 0, 0, 0);
          accs[h][j] = __builtin_amdgcn_mfma_f32_16x16x32_bf16(
              a1, ld_frag(kp + h * 64 + 32 + quad * 8), accs[h][j], 0, 0, 0);
        }
      }
    }

    // ---- per output head: mix + res bilinear + online softmax + PV ----
    #pragma unroll
    for (int o = 0; o < 6; o++) {
      const float* zo = Z + ((size_t)(b * 6 + o)) * 153664;
      float f[2][4];
      #pragma unroll
      for (int j = 0; j < 2; j++) {
        if (j < nj) {
          const int t = t0 + j * 16 + r;
          #pragma unroll
          for (int i = 0; i < 4; i++) {
            float v = bfu[o];
            #pragma unroll
            for (int h = 0; h < 6; h++) v += wfs[o][h] * accs[h][j][i];
            const float z00 = zo[p00a[i] + t];
            const float z01 = zo[p01a[i] + t];
            const float z10 = zo[p10a[i] + t];
            const float z11 = zo[p10a[i] + p01a[i] - p00a[i] + t];
            const float r0 = z00 + fxa[i] * (z01 - z00);
            const float r1 = z10 + fxa[i] * (z11 - z10);
            f[j][i] = v + r0 + fya[i] * (r1 - r0);
          }
        } else {
          #pragma unroll
          for (int i = 0; i < 4; i++) f[j][i] = -1e30f;
        }
      }
      // wave max (all 64 lanes: per-wave m is valid since rows share m,
      // per-row normalization restored by srow)
      float mx = fmaxf(fmaxf(fmaxf(f[0][0], f[0][1]), fmaxf(f[0][2], f[0][3])),
                       fmaxf(fmaxf(f[1][0], f[1][1]), fmaxf(f[1][2], f[1][3])));
      #pragma unroll
      for (int off = 32; off >= 1; off >>= 1)
        mx = fmaxf(mx, __shfl_xor(mx, off));
      if (mx > mo[o] + 8.f) {               // deferred-max rescale (THR=8)
        const float sc = __expf(mo[o] - mx);
        mo[o] = mx;
        #pragma unroll
        for (int nt = 0; nt < 4; nt++) accp[o][nt] *= sc;
        #pragma unroll
        for (int i = 0; i < 4; i++) srow[o][i] *= sc;
      }
      #pragma unroll
      for (int j = 0; j < 2; j++) {
        #pragma unroll
        for (int i = 0; i < 4; i++) {
          const float p = __expf(f[j][i] - mo[o]);   // <= e^8; tail j -> 0
          srow[o][i] += p;
          Pl[w][quad * 4 + i][j * 16 + r] = f2bf(p);
        }
      }
      // PV: A = P from this wave's LDS tile, B = V direct (L2-hot).
      // Tail (t0=768): quad0 k=768..775, quad1 k=776..783 (clamp must allow
      // 776! 776+8=784 stays in-row); quads 2,3 have P==0, clamp them to 776.
      const bf16x8 pa = *(const bf16x8*)&Pl[w][r][quad * 8];
      const int vt0 = min(t0 + quad * 8, 776);
      const ushort_t* vp = Vt + ((size_t)(b * 384 + o * 64 + r)) * 784 + vt0;
      #pragma unroll
      for (int nt = 0; nt < 4; nt++)
        accp[o][nt] = __builtin_amdgcn_mfma_f32_16x16x32_bf16(
            pa, ld_frag(vp + (size_t)nt * 16 * 784), accp[o][nt], 0, 0, 0);
    }
  }

  // ---- epilogue: reduce row sums over the 16 columns lanes ----
  #pragma unroll
  for (int o = 0; o < 6; o++)
    #pragma unroll
    for (int i = 0; i < 4; i++)
      #pragma unroll
      for (int m = 1; m <= 8; m <<= 1)
        srow[o][i] += __shfl_xor(srow[o][i], m);

  if (lane == 0) {
    #pragma unroll
    for (int o = 0; o < 6; o++) wmbuf[w][o] = mo[o];
  }
  __syncthreads();

  const int orow = tid >> 4, ocol = (tid & 15) << 2;
  #pragma unroll
  for (int o = 0; o < 6; o++) {
    const float M = fmaxf(fmaxf(wmbuf[0][o], wmbuf[1][o]),
                          fmaxf(wmbuf[2][o], wmbuf[3][o]));
    const float ew = __expf(mo[o] - M);
    #pragma unroll
    for (int nt = 0; nt < 4; nt++)
      #pragma unroll
      for (int i = 0; i < 4; i++)
        accbuf[w][quad * 4 + i][nt * 16 + r] = accp[o][nt][i] * ew;
    if (r == 0) {
      #pragma unroll
      for (int i = 0; i < 4; i++) sbuf[w][quad * 4 + i] = srow[o][i] * ew;
    }
    __syncthreads();
    const float st = sbuf[0][orow] + sbuf[1][orow] + sbuf[2][orow] + sbuf[3][orow];
    const float inv = 1.f / st;
    ushort_t pk[4];
    #pragma unroll
    for (int e = 0; e < 4; e++) {
      const float v = (accbuf[0][orow][ocol + e] + accbuf[1][orow][ocol + e]
                     + accbuf[2][orow][ocol + e] + accbuf[3][orow][ocol + e]) * inv;
      pk[e] = f2bf(v);
    }
    uint2 w2;
    w2.x = (uint)pk[0] | ((uint)pk[1] << 16);
    w2.y = (uint)pk[2] | ((uint)pk[3] << 16);
    *(uint2*)(O + ((size_t)(b * 784) + l0 + orow) * 384 + o * 64 + ocol) = w2;
    __syncthreads();
  }
}

// ---------- host launcher ----------
extern "C" void kernel_launch(void* const* d_in, const int* in_sizes, int n_in,
                              void* d_out, int out_size, void* d_ws, size_t ws_size,
                              hipStream_t stream)
{
  const float* x        = (const float*)d_in[0];
  const float* res_attn = (const float*)d_in[1];
  const float* conv_w   = (const float*)d_in[2];
  const float* ln_g     = (const float*)d_in[3];
  const float* ln_b     = (const float*)d_in[4];
  const float* wq       = (const float*)d_in[5];
  const float* wk       = (const float*)d_in[6];
  const float* wv       = (const float*)d_in[7];
  const float* w_proj   = (const float*)d_in[8];
  const float* b_proj   = (const float*)d_in[9];
  const float* w_fuse   = (const float*)d_in[10];
  const float* b_fuse   = (const float*)d_in[11];
  float* out = (float*)d_out;

  // ws layout (bf16 elements), ~60 MB total
  const size_t NE = (size_t)8 * 784 * 384;      // 2,408,448
  const size_t NW = 147456;
  ushort_t* q_ln_b = (ushort_t*)d_ws;
  ushort_t* kv_b   = q_ln_b + NE;
  ushort_t* Qb     = kv_b + NE;
  ushort_t* Kb     = Qb + NE;
  ushort_t* Vt     = Kb + NE;   // (b, 384, 784)
  ushort_t* Opre   = Vt + NE;
  ushort_t* wqb    = Opre + NE;
  ushort_t* wkb    = wqb + NW;
  ushort_t* wvb    = wkb + NW;
  ushort_t* wpb    = wvb + NW;
  float*    Z      = (float*)(wpb + NW);  // premixed res (b,6,196,784) f32, 16B-aligned

  k_premix<<<dim3(1201),   dim3(256), 0, stream>>>(res_attn, w_fuse, Z);
  k_convln<<<dim3(8 * 784), dim3(384), 0, stream>>>(x, conv_w, ln_g, ln_b, q_ln_b);
  k_pool  <<<dim3(9408),    dim3(256), 0, stream>>>(x, kv_b);
  k_wcvt  <<<dim3(576),     dim3(256), 0, stream>>>(wq, wk, wv, w_proj, wqb, wkb, wvb, wpb);

  k_gemm<0><<<dim3(3, 49), dim3(256), 0, stream>>>(q_ln_b, wqb, nullptr, Qb);
  k_gemm<0><<<dim3(3, 49), dim3(256), 0, stream>>>(kv_b,   wkb, nullptr, Kb);
  k_gemm<1><<<dim3(3, 49), dim3(256), 0, stream>>>(kv_b,   wvb, nullptr, Vt);

  k_flash<<<dim3(49, 8), dim3(256), 0, stream>>>(Qb, Kb, Vt, Z, w_fuse, b_fuse, Opre);

  k_gemm<2><<<dim3(3, 49), dim3(256), 0, stream>>>(Opre, wpb, b_proj, out);
}